// Round 4
// baseline (543.636 us; speedup 1.0000x reference)
//
#include <hip/hip_runtime.h>
#include <math.h>

typedef __attribute__((ext_vector_type(8))) short bf16x8;
typedef __attribute__((ext_vector_type(4))) float f32x4;

constexpr int kN   = 50000;
constexpr int kR   = 8;
constexpr int kIn  = 128;
constexpr int kHid = 128;
constexpr int kOut = 40;
constexpr int kNT  = 16;              // dst nodes per block
constexpr int kLds = 1032;            // ushort row stride: 1024 + 8 pad (16B-aligned rows)
constexpr float kBnEps = 1e-5f;

// bf16 helpers (RNE), bitwise to avoid header type friction
__device__ inline ushort f2bf(float x) {
    uint u = __float_as_uint(x);
    u += 0x7FFFu + ((u >> 16) & 1u);
    return (ushort)(u >> 16);
}
__device__ inline float bf2f(ushort s) { return __uint_as_float(((uint)s) << 16); }

// ---------------------------------------------------------------------------
// Pack W (fp32 [1024][N]) into MFMA B-fragment order, split hi/lo bf16.
// Fragment f = nt*32 + kt; lane L holds B[n = nt*16 + (L&15)][k = kt*32 + (L>>4)*8 + j].
// ---------------------------------------------------------------------------
__global__ void pack_w(const float* __restrict__ W, ushort* __restrict__ hi,
                       ushort* __restrict__ lo, int N)
{
    const int lane = threadIdx.x;                 // 64
    const int kt = blockIdx.x & 31;
    const int nt = blockIdx.x >> 5;
    const int n  = nt * 16 + (lane & 15);
    const int q  = lane >> 4;
    ushort hv[8], lv[8];
    #pragma unroll
    for (int j = 0; j < 8; ++j) {
        const int k = kt * 32 + q * 8 + j;
        const float w = (n < N) ? W[(size_t)k * N + n] : 0.f;
        const ushort h = f2bf(w);
        hv[j] = h;
        lv[j] = f2bf(w - bf2f(h));
    }
    const size_t o = ((size_t)blockIdx.x * 64 + lane) * 8;
    *(ushort4*)&hi[o]     = make_ushort4(hv[0], hv[1], hv[2], hv[3]);
    *(ushort4*)&hi[o + 4] = make_ushort4(hv[4], hv[5], hv[6], hv[7]);
    *(ushort4*)&lo[o]     = make_ushort4(lv[0], lv[1], lv[2], lv[3]);
    *(ushort4*)&lo[o + 4] = make_ushort4(lv[4], lv[5], lv[6], lv[7]);
}

// ---------------------------------------------------------------------------
// Branch-select accumulate (et is wave-uniform scalar)
// ---------------------------------------------------------------------------
__device__ inline void accum_sel(float2 acc[kR], int et, float2 w)
{
    if      (et == 0) { acc[0].x += w.x; acc[0].y += w.y; }
    else if (et == 1) { acc[1].x += w.x; acc[1].y += w.y; }
    else if (et == 2) { acc[2].x += w.x; acc[2].y += w.y; }
    else if (et == 3) { acc[3].x += w.x; acc[3].y += w.y; }
    else if (et == 4) { acc[4].x += w.x; acc[4].y += w.y; }
    else if (et == 5) { acc[5].x += w.x; acc[5].y += w.y; }
    else if (et == 6) { acc[6].x += w.x; acc[6].y += w.y; }
    else              { acc[7].x += w.x; acc[7].y += w.y; }
}

__device__ inline void store_agg(ushort (*aggHi)[kLds], ushort (*aggLo)[kLds],
                                 int n, int d2, const float2 acc[kR])
{
    #pragma unroll
    for (int r = 0; r < kR; ++r) {
        const ushort h0 = f2bf(acc[r].x);
        const ushort h1 = f2bf(acc[r].y);
        const ushort l0 = f2bf(acc[r].x - bf2f(h0));
        const ushort l1 = f2bf(acc[r].y - bf2f(h1));
        *(ushort2*)&aggHi[n][r * 128 + d2] = make_ushort2(h0, h1);
        *(ushort2*)&aggLo[n][r * 128 + d2] = make_ushort2(l0, l1);
    }
}

// ---------------------------------------------------------------------------
// Phase A: 8 waves, 2 dst nodes per wave. ALL 32 gathers (both nodes) are
// issued in one basic block before any branchy accumulation -> single vmcnt
// window instead of 4 chained load->branch->load sequences.
// ---------------------------------------------------------------------------
template <bool BF16IN>
__device__ inline void phaseA(const void* __restrict__ featv,
                              const int* __restrict__ ptr,
                              const int* __restrict__ idx,
                              const int* __restrict__ etype,
                              int base,
                              ushort (*aggHi)[kLds], ushort (*aggLo)[kLds])
{
    const int tid  = threadIdx.x;
    const int lane = tid & 63;
    const int wid  = tid >> 6;            // 8 waves
    const int d2   = lane * 2;

    const int n0 = wid * 2, n1 = n0 + 1;
    const int nodeA = base + n0;
    const int pA = ptr[nodeA];
    const int pB = ptr[nodeA + 1];
    const int pC = ptr[nodeA + 2];
    const int degA = pB - pA, degB = pC - pB;

    float2 accA[kR], accB[kR];
    #pragma unroll
    for (int r = 0; r < kR; ++r) {
        accA[r] = make_float2(0.f, 0.f);
        accB[r] = make_float2(0.f, 0.f);
    }

    if (degA == 16 && degB == 16) {       // fixed-degree fast path (always hit)
        const int e16 = lane & 15;
        const int viA = idx[pA + e16];
        const int veA = etype[pA + e16];
        const int viB = idx[pB + e16];
        const int veB = etype[pB + e16];

        float2 vA[16], vB[16];
        #pragma unroll
        for (int j = 0; j < 16; ++j) {    // all 32 loads independent
            const int srcA = __builtin_amdgcn_readlane(viA, j);
            const int srcB = __builtin_amdgcn_readlane(viB, j);
            if (BF16IN) {
                const ushort2 ua = *(const ushort2*)((const ushort*)featv + (size_t)srcA * kIn + d2);
                const ushort2 ub = *(const ushort2*)((const ushort*)featv + (size_t)srcB * kIn + d2);
                vA[j] = make_float2(bf2f(ua.x), bf2f(ua.y));
                vB[j] = make_float2(bf2f(ub.x), bf2f(ub.y));
            } else {
                vA[j] = *(const float2*)((const float*)featv + (size_t)srcA * kIn + d2);
                vB[j] = *(const float2*)((const float*)featv + (size_t)srcB * kIn + d2);
            }
        }
        #pragma unroll
        for (int j = 0; j < 16; ++j)
            accum_sel(accA, __builtin_amdgcn_readlane(veA, j), vA[j]);
        #pragma unroll
        for (int j = 0; j < 16; ++j)
            accum_sel(accB, __builtin_amdgcn_readlane(veB, j), vB[j]);
    } else {                              // generic fallback (never hit in bench)
        for (int e = pA; e < pB; ++e) {
            const int src = __builtin_amdgcn_readfirstlane(idx[e]);
            const int et  = __builtin_amdgcn_readfirstlane(etype[e]);
            float2 w;
            if (BF16IN) {
                const ushort2 u = *(const ushort2*)((const ushort*)featv + (size_t)src * kIn + d2);
                w = make_float2(bf2f(u.x), bf2f(u.y));
            } else {
                w = *(const float2*)((const float*)featv + (size_t)src * kIn + d2);
            }
            accum_sel(accA, et, w);
        }
        for (int e = pB; e < pC; ++e) {
            const int src = __builtin_amdgcn_readfirstlane(idx[e]);
            const int et  = __builtin_amdgcn_readfirstlane(etype[e]);
            float2 w;
            if (BF16IN) {
                const ushort2 u = *(const ushort2*)((const ushort*)featv + (size_t)src * kIn + d2);
                w = make_float2(bf2f(u.x), bf2f(u.y));
            } else {
                w = *(const float2*)((const float*)featv + (size_t)src * kIn + d2);
            }
            accum_sel(accB, et, w);
        }
    }

    store_agg(aggHi, aggLo, n0, d2, accA);
    store_agg(aggHi, aggLo, n1, d2, accB);
}

// ---------------------------------------------------------------------------
// Layer 1: h1 = bf16( relu(bn( (sum_r agg_r @ W1[r]) / deg )) )
// Phase B: wave w owns n-tile w (16 channels): 3 MFMA + 2 W-frag loads per kt.
// ---------------------------------------------------------------------------
__global__ __launch_bounds__(512, 4)
void rgcn_layer1(const float* __restrict__ x,
                 const ushort* __restrict__ W1hi, const ushort* __restrict__ W1lo,
                 const float* __restrict__ gamma, const float* __restrict__ beta,
                 const float* __restrict__ mean,  const float* __restrict__ var,
                 const int* __restrict__ ptr, const int* __restrict__ idx,
                 const int* __restrict__ etype,
                 ushort* __restrict__ h1b)
{
    __shared__ ushort aggHi[kNT][kLds];
    __shared__ ushort aggLo[kNT][kLds];
    const int tid  = threadIdx.x;
    const int base = blockIdx.x * kNT;

    phaseA<false>(x, ptr, idx, etype, base, aggHi, aggLo);
    __syncthreads();

    const int lane = tid & 63;
    const int wid  = tid >> 6;                   // n-tile owned by this wave
    const int m    = lane & 15;
    const int q    = lane >> 4;

    const bf16x8* Bh = (const bf16x8*)W1hi;
    const bf16x8* Bl = (const bf16x8*)W1lo;

    f32x4 acc = {0.f, 0.f, 0.f, 0.f};

    #pragma unroll 4
    for (int kt = 0; kt < 32; ++kt) {
        const bf16x8 ah = *(const bf16x8*)&aggHi[m][kt * 32 + q * 8];
        const bf16x8 al = *(const bf16x8*)&aggLo[m][kt * 32 + q * 8];
        const bf16x8 bh = Bh[((size_t)wid * 32 + kt) * 64 + lane];
        const bf16x8 bl = Bl[((size_t)wid * 32 + kt) * 64 + lane];
        acc = __builtin_amdgcn_mfma_f32_16x16x32_bf16(ah, bh, acc, 0, 0, 0);
        acc = __builtin_amdgcn_mfma_f32_16x16x32_bf16(al, bh, acc, 0, 0, 0);
        acc = __builtin_amdgcn_mfma_f32_16x16x32_bf16(ah, bl, acc, 0, 0, 0);
    }

    // Epilogue: deg norm + BN + ReLU, write bf16 h1
    const int c = wid * 16 + m;                  // channel (D col)
    const float g  = gamma[c] * rsqrtf(var[c] + kBnEps);
    const float mu = mean[c];
    const float bt = beta[c];
    #pragma unroll
    for (int i = 0; i < 4; ++i) {
        const int node = base + q * 4 + i;       // D row
        const float invdeg = 1.0f / (float)(ptr[node + 1] - ptr[node]);
        float v = (acc[i] * invdeg - mu) * g + bt;
        v = fmaxf(v, 0.f);
        h1b[(size_t)node * kHid + c] = f2bf(v);
    }
}

// ---------------------------------------------------------------------------
// Layer 2: out = log_softmax( (sum_r agg_r @ W2[r]) / deg ), N padded 40->48
// ---------------------------------------------------------------------------
__global__ __launch_bounds__(512, 4)
void rgcn_layer2(const ushort* __restrict__ h1b,
                 const ushort* __restrict__ W2hi, const ushort* __restrict__ W2lo,
                 const int* __restrict__ ptr, const int* __restrict__ idx,
                 const int* __restrict__ etype,
                 float* __restrict__ out)
{
    __shared__ ushort aggHi[kNT][kLds];
    __shared__ ushort aggLo[kNT][kLds];
    __shared__ float logits[kNT][48];
    const int tid  = threadIdx.x;
    const int base = blockIdx.x * kNT;

    phaseA<true>(h1b, ptr, idx, etype, base, aggHi, aggLo);
    __syncthreads();

    const int lane = tid & 63;
    const int wid  = tid >> 6;
    const int m    = lane & 15;
    const int q    = lane >> 4;

    if (wid < 3) {                               // n-tiles 0..2 cover 48 cols
        const bf16x8* Bh = (const bf16x8*)W2hi;
        const bf16x8* Bl = (const bf16x8*)W2lo;
        f32x4 acc = {0.f, 0.f, 0.f, 0.f};
        #pragma unroll 4
        for (int kt = 0; kt < 32; ++kt) {
            const bf16x8 ah = *(const bf16x8*)&aggHi[m][kt * 32 + q * 8];
            const bf16x8 al = *(const bf16x8*)&aggLo[m][kt * 32 + q * 8];
            const bf16x8 bh = Bh[((size_t)wid * 32 + kt) * 64 + lane];
            const bf16x8 bl = Bl[((size_t)wid * 32 + kt) * 64 + lane];
            acc = __builtin_amdgcn_mfma_f32_16x16x32_bf16(ah, bh, acc, 0, 0, 0);
            acc = __builtin_amdgcn_mfma_f32_16x16x32_bf16(al, bh, acc, 0, 0, 0);
            acc = __builtin_amdgcn_mfma_f32_16x16x32_bf16(ah, bl, acc, 0, 0, 0);
        }
        const int n = wid * 16 + m;              // logit column
        if (n < kOut) {
            #pragma unroll
            for (int i = 0; i < 4; ++i) {
                const int node = base + q * 4 + i;
                const float invdeg = 1.0f / (float)(ptr[node + 1] - ptr[node]);
                logits[q * 4 + i][n] = acc[i] * invdeg;
            }
        }
    }
    __syncthreads();

    // log_softmax: wave w handles nodes w*2, w*2+1
    #pragma unroll
    for (int i = 0; i < 2; ++i) {
        const int nrow = wid * 2 + i;
        const int node = base + nrow;
        const float v = (lane < kOut) ? logits[nrow][lane] : -INFINITY;
        float mx = v;
        #pragma unroll
        for (int off = 32; off > 0; off >>= 1)
            mx = fmaxf(mx, __shfl_xor(mx, off, 64));
        float s = (lane < kOut) ? __expf(v - mx) : 0.f;
        #pragma unroll
        for (int off = 32; off > 0; off >>= 1)
            s += __shfl_xor(s, off, 64);
        if (lane < kOut)
            out[(size_t)node * kOut + lane] = v - mx - __logf(s);
    }
}

// ---------------------------------------------------------------------------
extern "C" void kernel_launch(void* const* d_in, const int* in_sizes, int n_in,
                              void* d_out, int out_size, void* d_ws, size_t ws_size,
                              hipStream_t stream)
{
    const float* x     = (const float*)d_in[0];
    const float* W1    = (const float*)d_in[1];
    const float* W2    = (const float*)d_in[2];
    const float* gamma = (const float*)d_in[3];
    const float* beta  = (const float*)d_in[4];
    const float* mean  = (const float*)d_in[5];
    const float* var   = (const float*)d_in[6];
    const int*   ptr   = (const int*)d_in[7];
    const int*   idx   = (const int*)d_in[8];
    const int*   et    = (const int*)d_in[9];
    float*       out   = (float*)d_out;

    // Workspace layout (proven-safe budget: 25.6 MB used in R1)
    char* ws = (char*)d_ws;
    ushort* h1b  = (ushort*)ws;                              // 50000*128*2 = 12,800,000 B
    ushort* W1hi = (ushort*)(ws + 12800000);                 // 1024*128*2  =    262,144 B
    ushort* W1lo = (ushort*)(ws + 12800000 + 262144);
    ushort* W2hi = (ushort*)(ws + 12800000 + 524288);        // 1024*48*2   =     98,304 B
    ushort* W2lo = (ushort*)(ws + 12800000 + 524288 + 98304);

    pack_w<<<dim3(8 * 32), dim3(64), 0, stream>>>(W1, W1hi, W1lo, kHid);
    pack_w<<<dim3(3 * 32), dim3(64), 0, stream>>>(W2, W2hi, W2lo, kOut);

    dim3 grid(kN / kNT), block(512);
    rgcn_layer1<<<grid, block, 0, stream>>>(x, W1hi, W1lo, gamma, beta, mean, var,
                                            ptr, idx, et, h1b);
    rgcn_layer2<<<grid, block, 0, stream>>>(h1b, W2hi, W2lo, ptr, idx, et, out);
}

// Round 5
// 298.239 us; speedup vs baseline: 1.8228x; 1.8228x over previous
//
#include <hip/hip_runtime.h>
#include <math.h>

typedef __attribute__((ext_vector_type(8))) short bf16x8;
typedef __attribute__((ext_vector_type(4))) float f32x4;

constexpr int kN   = 50000;
constexpr int kR   = 8;
constexpr int kIn  = 128;
constexpr int kHid = 128;
constexpr int kOut = 40;
constexpr int kNT  = 16;              // dst nodes per block
constexpr int kLds = 1032;            // ushort row stride: 1024 + 8 pad
constexpr float kBnEps = 1e-5f;

// bf16 helpers (RNE)
__device__ inline ushort f2bf(float x) {
    uint u = __float_as_uint(x);
    u += 0x7FFFu + ((u >> 16) & 1u);
    return (ushort)(u >> 16);
}
__device__ inline float bf2f(ushort s) { return __uint_as_float(((uint)s) << 16); }

// ---------------------------------------------------------------------------
// Pack W (fp32 [1024][N]) into MFMA B-fragment order (bf16, RNE).
// Fragment f = nt*32 + kt; lane L holds B[n = nt*16 + (L&15)][k = kt*32 + (L>>4)*8 + j].
// ---------------------------------------------------------------------------
__global__ void pack_w(const float* __restrict__ W, ushort* __restrict__ hi, int N)
{
    const int lane = threadIdx.x;                 // 64
    const int kt = blockIdx.x & 31;
    const int nt = blockIdx.x >> 5;
    const int n  = nt * 16 + (lane & 15);
    const int q  = lane >> 4;
    ushort hv[8];
    #pragma unroll
    for (int j = 0; j < 8; ++j) {
        const int k = kt * 32 + q * 8 + j;
        hv[j] = f2bf((n < N) ? W[(size_t)k * N + n] : 0.f);
    }
    const size_t o = ((size_t)blockIdx.x * 64 + lane) * 8;
    *(ushort4*)&hi[o]     = make_ushort4(hv[0], hv[1], hv[2], hv[3]);
    *(ushort4*)&hi[o + 4] = make_ushort4(hv[4], hv[5], hv[6], hv[7]);
}

// ---------------------------------------------------------------------------
// Branch-select accumulate (et is wave-uniform scalar -> scalar branches)
// ---------------------------------------------------------------------------
__device__ inline void accum_sel(float2 acc[kR], int et, float2 w)
{
    if      (et == 0) { acc[0].x += w.x; acc[0].y += w.y; }
    else if (et == 1) { acc[1].x += w.x; acc[1].y += w.y; }
    else if (et == 2) { acc[2].x += w.x; acc[2].y += w.y; }
    else if (et == 3) { acc[3].x += w.x; acc[3].y += w.y; }
    else if (et == 4) { acc[4].x += w.x; acc[4].y += w.y; }
    else if (et == 5) { acc[5].x += w.x; acc[5].y += w.y; }
    else if (et == 6) { acc[6].x += w.x; acc[6].y += w.y; }
    else              { acc[7].x += w.x; acc[7].y += w.y; }
}

template <bool BF16IN>
__device__ inline float2 loadf2(const void* featv, int src, int d2)
{
    if (BF16IN) {
        const ushort2 u = *(const ushort2*)((const ushort*)featv + (size_t)src * kIn + d2);
        return make_float2(bf2f(u.x), bf2f(u.y));
    } else {
        return *(const float2*)((const float*)featv + (size_t)src * kIn + d2);
    }
}

// Fixed-degree fast path for one node: 4-edge chunked software pipeline.
// Live set: buf 16 VGPR + acc 16 VGPR + temps -> no spill at cap 85.
template <bool BF16IN>
__device__ inline void phaseA_node16(const void* featv, int p0, int lane, int d2,
                                     const int* __restrict__ idx,
                                     const int* __restrict__ etype,
                                     float2 acc[kR])
{
    const int e16 = lane & 15;
    const int vi = idx[p0 + e16];
    const int ve = etype[p0 + e16];
    float2 buf[8];
    #pragma unroll
    for (int j = 0; j < 8; ++j)                  // chunks 0,1 in flight
        buf[j] = loadf2<BF16IN>(featv, __builtin_amdgcn_readlane(vi, j), d2);
    #pragma unroll
    for (int j = 0; j < 4; ++j)
        accum_sel(acc, __builtin_amdgcn_readlane(ve, j), buf[j]);
    #pragma unroll
    for (int j = 0; j < 4; ++j)                  // chunk 2
        buf[j] = loadf2<BF16IN>(featv, __builtin_amdgcn_readlane(vi, 8 + j), d2);
    #pragma unroll
    for (int j = 4; j < 8; ++j)
        accum_sel(acc, __builtin_amdgcn_readlane(ve, j - 4 + 4), buf[j]);
    #pragma unroll
    for (int j = 0; j < 4; ++j)                  // chunk 3
        buf[4 + j] = loadf2<BF16IN>(featv, __builtin_amdgcn_readlane(vi, 12 + j), d2);
    #pragma unroll
    for (int j = 0; j < 4; ++j)
        accum_sel(acc, __builtin_amdgcn_readlane(ve, 8 + j), buf[j]);
    #pragma unroll
    for (int j = 0; j < 4; ++j)
        accum_sel(acc, __builtin_amdgcn_readlane(ve, 12 + j), buf[4 + j]);
}

// ---------------------------------------------------------------------------
// Phase A: 8 waves, 2 dst nodes per wave SEQUENTIALLY (16 acc regs live).
// Result: bf16 agg in LDS (single precision A operand).
// ---------------------------------------------------------------------------
template <bool BF16IN>
__device__ inline void phaseA(const void* __restrict__ featv,
                              const int* __restrict__ ptr,
                              const int* __restrict__ idx,
                              const int* __restrict__ etype,
                              int base, ushort (*aggHi)[kLds])
{
    const int tid  = threadIdx.x;
    const int lane = tid & 63;
    const int wid  = tid >> 6;            // 8 waves
    const int d2   = lane * 2;

    #pragma unroll
    for (int t = 0; t < 2; ++t) {
        const int n    = wid + t * 8;
        const int node = base + n;
        const int p0   = ptr[node];
        const int deg  = ptr[node + 1] - p0;

        float2 acc[kR];
        #pragma unroll
        for (int r = 0; r < kR; ++r) acc[r] = make_float2(0.f, 0.f);

        if (deg == 16) {
            phaseA_node16<BF16IN>(featv, p0, lane, d2, idx, etype, acc);
        } else {                          // generic fallback (never hit in bench)
            for (int e = p0; e < p0 + deg; ++e) {
                const int src = __builtin_amdgcn_readfirstlane(idx[e]);
                const int et  = __builtin_amdgcn_readfirstlane(etype[e]);
                accum_sel(acc, et, loadf2<BF16IN>(featv, src, d2));
            }
        }
        #pragma unroll
        for (int r = 0; r < kR; ++r)
            *(ushort2*)&aggHi[n][r * 128 + d2] =
                make_ushort2(f2bf(acc[r].x), f2bf(acc[r].y));
    }
}

// ---------------------------------------------------------------------------
// Layer 1: h1 = bf16( relu(bn( (sum_r agg_r @ W1[r]) / deg )) )
// Phase B: wave w owns n-tile w (16 channels): 1 bf16 MFMA + 1 W-frag per kt.
// ---------------------------------------------------------------------------
__global__ __launch_bounds__(512, 6)
void rgcn_layer1(const float* __restrict__ x,
                 const ushort* __restrict__ W1hi,
                 const float* __restrict__ gamma, const float* __restrict__ beta,
                 const float* __restrict__ mean,  const float* __restrict__ var,
                 const int* __restrict__ ptr, const int* __restrict__ idx,
                 const int* __restrict__ etype,
                 ushort* __restrict__ h1b)
{
    __shared__ ushort aggHi[kNT][kLds];           // 33 KB
    const int tid  = threadIdx.x;
    const int base = blockIdx.x * kNT;

    phaseA<false>(x, ptr, idx, etype, base, aggHi);
    __syncthreads();

    const int lane = tid & 63;
    const int wid  = tid >> 6;                    // n-tile owned by this wave
    const int m    = lane & 15;
    const int q    = lane >> 4;

    const bf16x8* Bh = (const bf16x8*)W1hi + (size_t)wid * 32 * 64 + lane;
    f32x4 acc = {0.f, 0.f, 0.f, 0.f};

    #pragma unroll 4
    for (int kt = 0; kt < 32; ++kt) {
        const bf16x8 ah = *(const bf16x8*)&aggHi[m][kt * 32 + q * 8];
        const bf16x8 bh = Bh[(size_t)kt * 64];
        acc = __builtin_amdgcn_mfma_f32_16x16x32_bf16(ah, bh, acc, 0, 0, 0);
    }

    // Epilogue: deg norm + BN + ReLU, write bf16 h1
    const int c = wid * 16 + m;
    const float g  = gamma[c] * rsqrtf(var[c] + kBnEps);
    const float mu = mean[c];
    const float bt = beta[c];
    #pragma unroll
    for (int i = 0; i < 4; ++i) {
        const int node = base + q * 4 + i;
        const float invdeg = 1.0f / (float)(ptr[node + 1] - ptr[node]);
        float v = (acc[i] * invdeg - mu) * g + bt;
        v = fmaxf(v, 0.f);
        h1b[(size_t)node * kHid + c] = f2bf(v);
    }
}

// ---------------------------------------------------------------------------
// Layer 2: out = log_softmax( (sum_r agg_r @ W2[r]) / deg ), N padded 40->48
// ---------------------------------------------------------------------------
__global__ __launch_bounds__(512, 6)
void rgcn_layer2(const ushort* __restrict__ h1b,
                 const ushort* __restrict__ W2hi,
                 const int* __restrict__ ptr, const int* __restrict__ idx,
                 const int* __restrict__ etype,
                 float* __restrict__ out)
{
    __shared__ ushort aggHi[kNT][kLds];           // 33 KB
    __shared__ float logits[kNT][48];             // 3 KB
    const int tid  = threadIdx.x;
    const int base = blockIdx.x * kNT;

    phaseA<true>(h1b, ptr, idx, etype, base, aggHi);
    __syncthreads();

    const int lane = tid & 63;
    const int wid  = tid >> 6;
    const int m    = lane & 15;
    const int q    = lane >> 4;

    if (wid < 3) {                                // n-tiles 0..2 cover 48 cols
        const bf16x8* Bh = (const bf16x8*)W2hi + (size_t)wid * 32 * 64 + lane;
        f32x4 acc = {0.f, 0.f, 0.f, 0.f};
        #pragma unroll 4
        for (int kt = 0; kt < 32; ++kt) {
            const bf16x8 ah = *(const bf16x8*)&aggHi[m][kt * 32 + q * 8];
            const bf16x8 bh = Bh[(size_t)kt * 64];
            acc = __builtin_amdgcn_mfma_f32_16x16x32_bf16(ah, bh, acc, 0, 0, 0);
        }
        const int n = wid * 16 + m;               // logit column
        if (n < kOut) {
            #pragma unroll
            for (int i = 0; i < 4; ++i) {
                const int node = base + q * 4 + i;
                const float invdeg = 1.0f / (float)(ptr[node + 1] - ptr[node]);
                logits[q * 4 + i][n] = acc[i] * invdeg;
            }
        }
    }
    __syncthreads();

    // log_softmax: wave w handles nodes w*2, w*2+1
    #pragma unroll
    for (int i = 0; i < 2; ++i) {
        const int nrow = wid * 2 + i;
        const int node = base + nrow;
        const float v = (lane < kOut) ? logits[nrow][lane] : -INFINITY;
        float mx = v;
        #pragma unroll
        for (int off = 32; off > 0; off >>= 1)
            mx = fmaxf(mx, __shfl_xor(mx, off, 64));
        float s = (lane < kOut) ? __expf(v - mx) : 0.f;
        #pragma unroll
        for (int off = 32; off > 0; off >>= 1)
            s += __shfl_xor(s, off, 64);
        if (lane < kOut)
            out[(size_t)node * kOut + lane] = v - mx - __logf(s);
    }
}

// ---------------------------------------------------------------------------
extern "C" void kernel_launch(void* const* d_in, const int* in_sizes, int n_in,
                              void* d_out, int out_size, void* d_ws, size_t ws_size,
                              hipStream_t stream)
{
    const float* x     = (const float*)d_in[0];
    const float* W1    = (const float*)d_in[1];
    const float* W2    = (const float*)d_in[2];
    const float* gamma = (const float*)d_in[3];
    const float* beta  = (const float*)d_in[4];
    const float* mean  = (const float*)d_in[5];
    const float* var   = (const float*)d_in[6];
    const int*   ptr   = (const int*)d_in[7];
    const int*   idx   = (const int*)d_in[8];
    const int*   et    = (const int*)d_in[9];
    float*       out   = (float*)d_out;

    // Workspace layout (~13.2 MB; 25.6 MB proven safe)
    char* ws = (char*)d_ws;
    ushort* h1b  = (ushort*)ws;                              // 50000*128*2 = 12,800,000 B
    ushort* W1hi = (ushort*)(ws + 12800000);                 // 1024*128*2  =    262,144 B
    ushort* W2hi = (ushort*)(ws + 12800000 + 262144);        // 1024*48*2   =     98,304 B

    pack_w<<<dim3(8 * 32), dim3(64), 0, stream>>>(W1, W1hi, kHid);
    pack_w<<<dim3(3 * 32), dim3(64), 0, stream>>>(W2, W2hi, kOut);

    dim3 grid(kN / kNT), block(512);
    rgcn_layer1<<<grid, block, 0, stream>>>(x, W1hi, gamma, beta, mean, var,
                                            ptr, idx, et, h1b);
    rgcn_layer2<<<grid, block, 0, stream>>>(h1b, W2hi, ptr, idx, et, out);
}

// Round 6
// 200.573 us; speedup vs baseline: 2.7104x; 1.4869x over previous
//
#include <hip/hip_runtime.h>
#include <math.h>

typedef __attribute__((ext_vector_type(8))) short bf16x8;
typedef __attribute__((ext_vector_type(4))) float f32x4;

constexpr int kN   = 50000;
constexpr int kR   = 8;
constexpr int kIn  = 128;
constexpr int kHid = 128;
constexpr int kOut = 40;
constexpr int kNT  = 16;              // dst nodes per block
constexpr int kLds = 1032;            // ushort row stride (16B-aligned rows)
constexpr float kBnEps = 1e-5f;

// bf16 helpers (RNE)
__device__ inline ushort f2bf(float x) {
    uint u = __float_as_uint(x);
    u += 0x7FFFu + ((u >> 16) & 1u);
    return (ushort)(u >> 16);
}
__device__ inline float bf2f(ushort s) { return __uint_as_float(((uint)s) << 16); }

// ---------------------------------------------------------------------------
// Cast x fp32 -> bf16 (RNE). 6.4M elems = 3125 blocks x 256 thr x 8 elems.
// ---------------------------------------------------------------------------
__global__ void cast_x(const float* __restrict__ x, ushort* __restrict__ xb)
{
    const size_t i = ((size_t)blockIdx.x * 256 + threadIdx.x) * 8;
    const float4 v0 = *(const float4*)&x[i];
    const float4 v1 = *(const float4*)&x[i + 4];
    *(ushort4*)&xb[i]     = make_ushort4(f2bf(v0.x), f2bf(v0.y), f2bf(v0.z), f2bf(v0.w));
    *(ushort4*)&xb[i + 4] = make_ushort4(f2bf(v1.x), f2bf(v1.y), f2bf(v1.z), f2bf(v1.w));
}

// ---------------------------------------------------------------------------
// Pack W (fp32 [1024][N]) into MFMA B-fragment order (bf16, RNE).
// ---------------------------------------------------------------------------
__global__ void pack_w(const float* __restrict__ W, ushort* __restrict__ hi, int N)
{
    const int lane = threadIdx.x;                 // 64
    const int kt = blockIdx.x & 31;
    const int nt = blockIdx.x >> 5;
    const int n  = nt * 16 + (lane & 15);
    const int q  = lane >> 4;
    ushort hv[8];
    #pragma unroll
    for (int j = 0; j < 8; ++j) {
        const int k = kt * 32 + q * 8 + j;
        hv[j] = f2bf((n < N) ? W[(size_t)k * N + n] : 0.f);
    }
    const size_t o = ((size_t)blockIdx.x * 64 + lane) * 8;
    *(ushort4*)&hi[o]     = make_ushort4(hv[0], hv[1], hv[2], hv[3]);
    *(ushort4*)&hi[o + 4] = make_ushort4(hv[4], hv[5], hv[6], hv[7]);
}

// ---------------------------------------------------------------------------
// Phase A: NO private arrays (named scalars only -> SROA-safe, no scratch).
// 8 waves x 2 sequential nodes; lane owns bf16 pair d = lane*2, lane*2+1.
// All 16 gathers issued back-to-back, then wave-uniform branchy accumulate.
// ---------------------------------------------------------------------------
#define ACCUM_ET(ET, VX, VY)                                   \
    if      ((ET) == 0) { a0.x += (VX); a0.y += (VY); }        \
    else if ((ET) == 1) { a1.x += (VX); a1.y += (VY); }        \
    else if ((ET) == 2) { a2.x += (VX); a2.y += (VY); }        \
    else if ((ET) == 3) { a3.x += (VX); a3.y += (VY); }        \
    else if ((ET) == 4) { a4.x += (VX); a4.y += (VY); }        \
    else if ((ET) == 5) { a5.x += (VX); a5.y += (VY); }        \
    else if ((ET) == 6) { a6.x += (VX); a6.y += (VY); }        \
    else                { a7.x += (VX); a7.y += (VY); }

#define GATHER(BV, SRC) \
    const ushort2 BV = *(const ushort2*)&feat[(size_t)(SRC) * 128 + d2];

#define ACCUM_EDGE(J, BV) \
    { const int et = __builtin_amdgcn_readlane(ve, J); ACCUM_ET(et, bf2f(BV.x), bf2f(BV.y)) }

#define STORE_AGG(RR, AV) \
    *(ushort2*)&aggHi[n][(RR) * 128 + d2] = make_ushort2(f2bf(AV.x), f2bf(AV.y));

__device__ __forceinline__ void phaseA_bf16(const ushort* __restrict__ feat,
                                            const int* __restrict__ ptr,
                                            const int* __restrict__ idx,
                                            const int* __restrict__ etype,
                                            int base, ushort (*aggHi)[kLds])
{
    const int lane = threadIdx.x & 63;
    const int wid  = threadIdx.x >> 6;            // 8 waves
    const int d2   = lane * 2;

    #pragma unroll
    for (int t = 0; t < 2; ++t) {
        const int n    = wid * 2 + t;
        const int node = base + n;
        const int p0   = ptr[node];
        const int deg  = ptr[node + 1] - p0;

        float2 a0 = {0.f,0.f}, a1 = {0.f,0.f}, a2 = {0.f,0.f}, a3 = {0.f,0.f};
        float2 a4 = {0.f,0.f}, a5 = {0.f,0.f}, a6 = {0.f,0.f}, a7 = {0.f,0.f};

        if (deg == 16) {                          // fixed-degree fast path
            const int vi = idx[p0 + (lane & 15)];
            const int ve = etype[p0 + (lane & 15)];
            const int s0  = __builtin_amdgcn_readlane(vi, 0);
            const int s1  = __builtin_amdgcn_readlane(vi, 1);
            const int s2  = __builtin_amdgcn_readlane(vi, 2);
            const int s3  = __builtin_amdgcn_readlane(vi, 3);
            const int s4  = __builtin_amdgcn_readlane(vi, 4);
            const int s5  = __builtin_amdgcn_readlane(vi, 5);
            const int s6  = __builtin_amdgcn_readlane(vi, 6);
            const int s7  = __builtin_amdgcn_readlane(vi, 7);
            const int s8  = __builtin_amdgcn_readlane(vi, 8);
            const int s9  = __builtin_amdgcn_readlane(vi, 9);
            const int s10 = __builtin_amdgcn_readlane(vi, 10);
            const int s11 = __builtin_amdgcn_readlane(vi, 11);
            const int s12 = __builtin_amdgcn_readlane(vi, 12);
            const int s13 = __builtin_amdgcn_readlane(vi, 13);
            const int s14 = __builtin_amdgcn_readlane(vi, 14);
            const int s15 = __builtin_amdgcn_readlane(vi, 15);
            GATHER(b0,  s0)  GATHER(b1,  s1)  GATHER(b2,  s2)  GATHER(b3,  s3)
            GATHER(b4,  s4)  GATHER(b5,  s5)  GATHER(b6,  s6)  GATHER(b7,  s7)
            GATHER(b8,  s8)  GATHER(b9,  s9)  GATHER(b10, s10) GATHER(b11, s11)
            GATHER(b12, s12) GATHER(b13, s13) GATHER(b14, s14) GATHER(b15, s15)
            ACCUM_EDGE(0,  b0)  ACCUM_EDGE(1,  b1)  ACCUM_EDGE(2,  b2)  ACCUM_EDGE(3,  b3)
            ACCUM_EDGE(4,  b4)  ACCUM_EDGE(5,  b5)  ACCUM_EDGE(6,  b6)  ACCUM_EDGE(7,  b7)
            ACCUM_EDGE(8,  b8)  ACCUM_EDGE(9,  b9)  ACCUM_EDGE(10, b10) ACCUM_EDGE(11, b11)
            ACCUM_EDGE(12, b12) ACCUM_EDGE(13, b13) ACCUM_EDGE(14, b14) ACCUM_EDGE(15, b15)
        } else {                                  // generic fallback (never hit)
            for (int e = p0; e < p0 + deg; ++e) {
                const int src = __builtin_amdgcn_readfirstlane(idx[e]);
                const int et  = __builtin_amdgcn_readfirstlane(etype[e]);
                const ushort2 u = *(const ushort2*)&feat[(size_t)src * 128 + d2];
                ACCUM_ET(et, bf2f(u.x), bf2f(u.y))
            }
        }
        STORE_AGG(0, a0) STORE_AGG(1, a1) STORE_AGG(2, a2) STORE_AGG(3, a3)
        STORE_AGG(4, a4) STORE_AGG(5, a5) STORE_AGG(6, a6) STORE_AGG(7, a7)
    }
}

// ---------------------------------------------------------------------------
// Layer 1: h1 = bf16( relu(bn( (sum_r agg_r @ W1[r]) / deg )) )
// ---------------------------------------------------------------------------
__global__ __launch_bounds__(512, 4)
void rgcn_layer1(const ushort* __restrict__ xb,
                 const ushort* __restrict__ W1hi,
                 const float* __restrict__ gamma, const float* __restrict__ beta,
                 const float* __restrict__ mean,  const float* __restrict__ var,
                 const int* __restrict__ ptr, const int* __restrict__ idx,
                 const int* __restrict__ etype,
                 ushort* __restrict__ h1b)
{
    __shared__ ushort aggHi[kNT][kLds];           // 33 KB
    const int tid  = threadIdx.x;
    const int base = blockIdx.x * kNT;

    phaseA_bf16(xb, ptr, idx, etype, base, aggHi);
    __syncthreads();

    const int lane = tid & 63;
    const int wid  = tid >> 6;                    // n-tile owned by this wave
    const int m    = lane & 15;
    const int q    = lane >> 4;

    const bf16x8* Bh = (const bf16x8*)W1hi + (size_t)wid * 32 * 64 + lane;
    f32x4 acc = {0.f, 0.f, 0.f, 0.f};

    #pragma unroll 4
    for (int kt = 0; kt < 32; ++kt) {
        const bf16x8 ah = *(const bf16x8*)&aggHi[m][kt * 32 + q * 8];
        const bf16x8 bh = Bh[(size_t)kt * 64];
        acc = __builtin_amdgcn_mfma_f32_16x16x32_bf16(ah, bh, acc, 0, 0, 0);
    }

    // Epilogue: deg norm + BN + ReLU, write bf16 h1
    const int c = wid * 16 + m;
    const float g  = gamma[c] * rsqrtf(var[c] + kBnEps);
    const float mu = mean[c];
    const float bt = beta[c];
    #pragma unroll
    for (int i = 0; i < 4; ++i) {
        const int node = base + q * 4 + i;
        const float invdeg = 1.0f / (float)(ptr[node + 1] - ptr[node]);
        float v = (acc[i] * invdeg - mu) * g + bt;
        v = fmaxf(v, 0.f);
        h1b[(size_t)node * kHid + c] = f2bf(v);
    }
}

// ---------------------------------------------------------------------------
// Layer 2: out = log_softmax( (sum_r agg_r @ W2[r]) / deg ), N padded 40->48
// ---------------------------------------------------------------------------
__global__ __launch_bounds__(512, 4)
void rgcn_layer2(const ushort* __restrict__ h1b,
                 const ushort* __restrict__ W2hi,
                 const int* __restrict__ ptr, const int* __restrict__ idx,
                 const int* __restrict__ etype,
                 float* __restrict__ out)
{
    __shared__ ushort aggHi[kNT][kLds];           // 33 KB
    __shared__ float logits[kNT][48];             // 3 KB
    const int tid  = threadIdx.x;
    const int base = blockIdx.x * kNT;

    phaseA_bf16(h1b, ptr, idx, etype, base, aggHi);
    __syncthreads();

    const int lane = tid & 63;
    const int wid  = tid >> 6;
    const int m    = lane & 15;
    const int q    = lane >> 4;

    if (wid < 3) {                                // n-tiles 0..2 cover 48 cols
        const bf16x8* Bh = (const bf16x8*)W2hi + (size_t)wid * 32 * 64 + lane;
        f32x4 acc = {0.f, 0.f, 0.f, 0.f};
        #pragma unroll 4
        for (int kt = 0; kt < 32; ++kt) {
            const bf16x8 ah = *(const bf16x8*)&aggHi[m][kt * 32 + q * 8];
            const bf16x8 bh = Bh[(size_t)kt * 64];
            acc = __builtin_amdgcn_mfma_f32_16x16x32_bf16(ah, bh, acc, 0, 0, 0);
        }
        const int n = wid * 16 + m;               // logit column
        if (n < kOut) {
            #pragma unroll
            for (int i = 0; i < 4; ++i) {
                const int node = base + q * 4 + i;
                const float invdeg = 1.0f / (float)(ptr[node + 1] - ptr[node]);
                logits[q * 4 + i][n] = acc[i] * invdeg;
            }
        }
    }
    __syncthreads();

    // log_softmax: wave w handles nodes w*2, w*2+1
    #pragma unroll
    for (int i = 0; i < 2; ++i) {
        const int nrow = wid * 2 + i;
        const int node = base + nrow;
        const float v = (lane < kOut) ? logits[nrow][lane] : -INFINITY;
        float mx = v;
        #pragma unroll
        for (int off = 32; off > 0; off >>= 1)
            mx = fmaxf(mx, __shfl_xor(mx, off, 64));
        float s = (lane < kOut) ? __expf(v - mx) : 0.f;
        #pragma unroll
        for (int off = 32; off > 0; off >>= 1)
            s += __shfl_xor(s, off, 64);
        if (lane < kOut)
            out[(size_t)node * kOut + lane] = v - mx - __logf(s);
    }
}

// ---------------------------------------------------------------------------
extern "C" void kernel_launch(void* const* d_in, const int* in_sizes, int n_in,
                              void* d_out, int out_size, void* d_ws, size_t ws_size,
                              hipStream_t stream)
{
    const float* x     = (const float*)d_in[0];
    const float* W1    = (const float*)d_in[1];
    const float* W2    = (const float*)d_in[2];
    const float* gamma = (const float*)d_in[3];
    const float* beta  = (const float*)d_in[4];
    const float* mean  = (const float*)d_in[5];
    const float* var   = (const float*)d_in[6];
    const int*   ptr   = (const int*)d_in[7];
    const int*   idx   = (const int*)d_in[8];
    const int*   et    = (const int*)d_in[9];
    float*       out   = (float*)d_out;

    // Workspace (~26 MB; 25.6 MB proven safe, xb replaces old fp32 h1 slot)
    char* ws = (char*)d_ws;
    ushort* h1b  = (ushort*)ws;                              // 12,800,000 B
    ushort* xb   = (ushort*)(ws + 12800000);                 // 12,800,000 B
    ushort* W1hi = (ushort*)(ws + 25600000);                 //    262,144 B
    ushort* W2hi = (ushort*)(ws + 25600000 + 262144);        //     98,304 B

    cast_x<<<dim3(3125), dim3(256), 0, stream>>>(x, xb);
    pack_w<<<dim3(8 * 32), dim3(64), 0, stream>>>(W1, W1hi, kHid);
    pack_w<<<dim3(3 * 32), dim3(64), 0, stream>>>(W2, W2hi, kOut);

    dim3 grid(kN / kNT), block(512);
    rgcn_layer1<<<grid, block, 0, stream>>>(xb, W1hi, gamma, beta, mean, var,
                                            ptr, idx, et, h1b);
    rgcn_layer2<<<grid, block, 0, stream>>>(h1b, W2hi, ptr, idx, et, out);
}